// Round 14
// baseline (620.706 us; speedup 1.0000x reference)
//
#include <hip/hip_runtime.h>
#include <cstdint>
#include <cstddef>

typedef __bf16 bf16x8_t __attribute__((ext_vector_type(8)));
typedef float f32x4 __attribute__((ext_vector_type(4)));

#define HID 3072
#define NHEADS 24
#define HD 128
#define MLP 12288
#define SEQ 1280
#define IMG 1024
#define N1 21504   /* 3*HID + MLP */
#define QKVW 9216  /* 3*HID */
#define A2W 15360  /* HID + MLP */
#define EPSV 1e-6f

// Tiled bf16 operand layout ("fragment-block" order):
// element (row, col) of a [rows][K] operand lives at:
//   tile (row>>8, col>>6) -> 16384-elem image of 32 blocks x 512 elems:
//   block = ((col>>5)&1)*16 + ((row>>4)&15)         (k32 , row16)
//   slot  = (row&15) + ((col>>3)&3)*16              (lane = lr + lg*16)
//   elem  = block*512 + slot*8 + (col&7)
__device__ __forceinline__ size_t tpos(int row, int col, int KT) {
    return ((size_t)(row >> 8) * KT + (col >> 6)) * 16384
         + (size_t)(((((col >> 5) & 1) << 4) + ((row >> 4) & 15)) * 512
                    + (((row & 15) + (((col >> 3) & 3) << 4)) << 3) + (col & 7));
}

__device__ __forceinline__ void gload16(const void* g, void* l) {
    __builtin_amdgcn_global_load_lds(
        (const __attribute__((address_space(1))) unsigned int*)g,
        (__attribute__((address_space(3))) unsigned int*)l, 16, 0, 0);
}

__device__ __forceinline__ void bar() {
    asm volatile("" ::: "memory");
    __builtin_amdgcn_s_barrier();
    asm volatile("" ::: "memory");
}

__device__ __forceinline__ float bf2f(uint u) {
    return __builtin_bit_cast(float, u << 16);
}
__device__ __forceinline__ ushort f2bfu(float f) {
    return __builtin_bit_cast(ushort, (__bf16)f);
}

// transpose-convert tile: in [K][N] f32 -> out tiled bf16 (rows=n, cols=k), 256 thr
__device__ __forceinline__ void conv_tile(const float* __restrict__ in, ushort* __restrict__ out,
                                          int N, int KT, int kb, int nb, int tid,
                                          float (*tle)[65]) {
    int k0 = kb * 64, n0 = nb * 64;
    int rr = tid >> 2, cg = (tid & 3) * 16;
    #pragma unroll
    for (int j = 0; j < 4; ++j) {
        float4 vv = *reinterpret_cast<const float4*>(&in[(size_t)(k0 + rr) * N + n0 + cg + j * 4]);
        tle[rr][cg + j * 4 + 0] = vv.x;
        tle[rr][cg + j * 4 + 1] = vv.y;
        tle[rr][cg + j * 4 + 2] = vv.z;
        tle[rr][cg + j * 4 + 3] = vv.w;
    }
    __syncthreads();
    int nl = tid & 63;
    #pragma unroll
    for (int gg = 0; gg < 2; ++gg) {
        int g = (tid >> 6) + gg * 4;
        union { ushort u[8]; uint4 q; } pk;
        #pragma unroll
        for (int j = 0; j < 8; ++j)
            pk.u[j] = f2bfu(tle[g * 8 + j][nl]);
        *reinterpret_cast<uint4*>(&out[tpos(n0 + nl, k0 + g * 8, KT)]) = pk.q;
    }
}

// ---------------- small kernels ----------------
__global__ void silu_kernel(const float* __restrict__ v, float* __restrict__ sv) {
    int i = blockIdx.x * 256 + threadIdx.x;
    float x = v[i];
    sv[i] = x / (1.f + expf(-x));
}

// fat: blocks [0,288) = mod-GEMV partials; [288, 288+16128) = convB(w1)
__global__ __launch_bounds__(256) void gemvconv_fat(const float* __restrict__ sv,
                                                    const float* __restrict__ W,
                                                    float* __restrict__ part,
                                                    const float* __restrict__ w1,
                                                    ushort* __restrict__ w1b) {
    __shared__ float tle[64][65];
    int bid = blockIdx.x;
    int tid = threadIdx.x;
    if (bid < 288) {
        int n = (bid % 36) * 256 + tid;
        int k0 = (bid / 36) * 384;
        float s = 0.f;
        for (int k = k0; k < k0 + 384; ++k)
            s = fmaf(sv[k], W[(size_t)k * QKVW + n], s);
        part[(size_t)(bid / 36) * QKVW + n] = s;
        return;
    }
    int cb = bid - 288;
    conv_tile(w1, w1b, N1, HID / 64, cb % 48, cb / 48, tid, tle);
}

__global__ void gemv_reduce(const float* __restrict__ part, const float* __restrict__ bias,
                            float* __restrict__ mod) {
    int n = blockIdx.x * 256 + threadIdx.x;
    float s = bias[n];
    #pragma unroll
    for (int ky = 0; ky < 8; ++ky) s += part[(size_t)ky * QKVW + n];
    mod[n] = s;
}

// LayerNorm + modulate -> bf16 x_mod (tiled layout). 384 threads, 1 row/block.
__global__ __launch_bounds__(384) void ln_mod_kernel(const float* __restrict__ x,
                                                     const float* __restrict__ mod,
                                                     ushort* __restrict__ xmt) {
    int m = blockIdx.x;
    int t = threadIdx.x;
    int lane = t & 63, w = t >> 6;
    const float* xr = x + (size_t)m * HID;
    float4 v0 = *reinterpret_cast<const float4*>(&xr[t * 8]);
    float4 v1 = *reinterpret_cast<const float4*>(&xr[t * 8 + 4]);
    float s = v0.x + v0.y + v0.z + v0.w + v1.x + v1.y + v1.z + v1.w;
    float sq = v0.x * v0.x + v0.y * v0.y + v0.z * v0.z + v0.w * v0.w +
               v1.x * v1.x + v1.y * v1.y + v1.z * v1.z + v1.w * v1.w;
    #pragma unroll
    for (int off = 1; off < 64; off <<= 1) {
        s += __shfl_xor(s, off);
        sq += __shfl_xor(sq, off);
    }
    __shared__ float red[12];
    if (lane == 0) { red[w] = s; red[w + 6] = sq; }
    __syncthreads();
    s = red[0] + red[1] + red[2] + red[3] + red[4] + red[5];
    sq = red[6] + red[7] + red[8] + red[9] + red[10] + red[11];
    float mu = s * (1.f / HID);
    float var = sq * (1.f / HID) - mu * mu;
    float rs = rsqrtf(var + EPSV);
    float vals[8] = {v0.x, v0.y, v0.z, v0.w, v1.x, v1.y, v1.z, v1.w};
    union { ushort u[8]; uint4 q; } pk;
    #pragma unroll
    for (int j = 0; j < 8; ++j) {
        int n = t * 8 + j;
        float y = (vals[j] - mu) * rs * (1.f + mod[HID + n]) + mod[n];
        pk.u[j] = f2bfu(y);
    }
    *reinterpret_cast<uint4*>(&xmt[tpos(m, t * 8, HID >> 6)]) = pk.q;
}

// ---------------- 256^2 GEMM, R6 schedule + early-B prefetch (ph1) --------
// EPI==1: n<9216 -> out1 = hqkv bf16 [row][col]; else gelu -> out2 = a2t tiled
// EPI==2: out1 = bf16 partials [(sp*SEQ+row)*HID + col]
template <int EPI, int SPLITS>
__global__ __launch_bounds__(512, 2) void gemm8p(
    const ushort* __restrict__ At, const ushort* __restrict__ Bt,
    const float* __restrict__ bias, ushort* __restrict__ out1, ushort* __restrict__ out2,
    int KTtot, int NTloc, int NTN) {
    int nwg = gridDim.x;
    int q = nwg >> 3, r = nwg & 7;
    int orig = blockIdx.x;
    int xcd = orig & 7;
    int wgid = (xcd < r ? xcd * (q + 1) : r * (q + 1) + (xcd - r) * q) + (orig >> 3);
    int mt = wgid % 5;
    int p = wgid / 5;
    int nt = p % NTN;
    int sp = p / NTN;
    int kOff = sp * NTloc;
    int m0 = mt * 256, n0 = nt * 256;

    __shared__ ushort LA[2][16384];
    __shared__ ushort LB[2][16384];

    int tid = threadIdx.x;
    int lane = tid & 63, wid = tid >> 6;
    int wm = wid >> 2, wn = wid & 3;
    int lr = lane & 15, lg = lane >> 4;

    const ushort* gA = At + (size_t)mt * KTtot * 16384;
    const ushort* gB = Bt + (size_t)nt * KTtot * 16384;

    f32x4 acc[8][4] = {};
    bf16x8_t af0[4][2], af1[4][2], bf0[2][2], bf1[2][2];

    auto stage = [&](ushort (*L)[16384], int buf, const ushort* g, int ktG) {
        #pragma unroll
        for (int j = 0; j < 4; ++j) {
            int b = wid * 4 + j;
            gload16(g + (size_t)ktG * 16384 + b * 512 + lane * 8, &L[buf][b * 512]);
        }
    };
    auto rdA = [&](int buf, int h, bf16x8_t (&af)[4][2]) {
        #pragma unroll
        for (int mi = 0; mi < 4; ++mi)
            #pragma unroll
            for (int k = 0; k < 2; ++k)
                af[mi][k] = *reinterpret_cast<const bf16x8_t*>(
                    &LA[buf][(k * 16 + wm * 8 + h * 4 + mi) * 512 + lane * 8]);
    };
    auto rdB = [&](int buf, int v, bf16x8_t (&bf)[2][2]) {
        #pragma unroll
        for (int ni = 0; ni < 2; ++ni)
            #pragma unroll
            for (int k = 0; k < 2; ++k)
                bf[ni][k] = *reinterpret_cast<const bf16x8_t*>(
                    &LB[buf][(k * 16 + wn * 4 + v * 2 + ni) * 512 + lane * 8]);
    };
    auto mmq = [&](bf16x8_t (&af)[4][2], bf16x8_t (&bf)[2][2], int h, int v) {
        __builtin_amdgcn_s_setprio(1);
        #pragma unroll
        for (int mi = 0; mi < 4; ++mi)
            #pragma unroll
            for (int ni = 0; ni < 2; ++ni)
                #pragma unroll
                for (int k = 0; k < 2; ++k)
                    acc[h * 4 + mi][v * 2 + ni] = __builtin_amdgcn_mfma_f32_16x16x32_bf16(
                        af[mi][k], bf[ni][k], acc[h * 4 + mi][v * 2 + ni], 0, 0, 0);
        __builtin_amdgcn_s_setprio(0);
    };

    stage(LA, 0, gA, kOff);
    stage(LB, 0, gB, kOff);
    stage(LA, 1, gA, kOff + 1);
    stage(LB, 1, gB, kOff + 1);
    asm volatile("s_waitcnt vmcnt(8)" ::: "memory");
    bar();
    rdA(0, 0, af0);
    rdB(0, 0, bf0);

    for (int t = 0; t < NTloc; ++t) {
        int c = t & 1;
        // ph0: reads of B-half1(t) ; MFMA (0,0)
        rdB(c, 1, bf1);
        mmq(af0, bf0, 0, 0);
        bar();
        // ph1: EARLY B(t+2) prefetch into cur buf (B region dead after ph0 reads)
        if (t + 2 < NTloc) stage(LB, c, gB, kOff + t + 2);
        rdA(c, 1, af1);
        mmq(af0, bf1, 0, 1);
        bar();
        // ph2: A(t+2) prefetch ; counted vmcnt guarantees tile t+1 landed
        if (t + 2 < NTloc) stage(LA, c, gA, kOff + t + 2);
        mmq(af1, bf0, 1, 0);
        if (t + 1 < NTloc) {
            if (t + 2 < NTloc) asm volatile("s_waitcnt vmcnt(8)" ::: "memory");
            else               asm volatile("s_waitcnt vmcnt(0)" ::: "memory");
        }
        bar();
        // ph3: first fragment reads of tile t+1 ; MFMA (1,1)
        if (t + 1 < NTloc) {
            rdA(c ^ 1, 0, af0);
            rdB(c ^ 1, 0, bf0);
        }
        mmq(af1, bf1, 1, 1);
        bar();
    }

    #pragma unroll
    for (int mi8 = 0; mi8 < 8; ++mi8) {
        #pragma unroll
        for (int nj = 0; nj < 4; ++nj) {
            int col = n0 + wn * 64 + nj * 16 + lr;
            #pragma unroll
            for (int rr2 = 0; rr2 < 4; ++rr2) {
                int row = m0 + wm * 128 + mi8 * 16 + lg * 4 + rr2;
                float val = acc[mi8][nj][rr2];
                if (EPI == 1) {
                    val += bias[col];
                    if (n0 < QKVW) {
                        out1[(size_t)row * QKVW + col] = f2bfu(val);
                    } else {
                        float u = 0.7978845608028654f * (val + 0.044715f * val * val * val);
                        float g = val / (1.f + __expf(-2.f * u));
                        out2[tpos(row, HID + (col - QKVW), A2W >> 6)] = f2bfu(g);
                    }
                } else {
                    out1[(size_t)(sp * SEQ + row) * HID + col] = f2bfu(val);
                }
            }
        }
    }
}

// out = x + (sum_s bf16 part[s] + bias) * gate ; 8 elems/thread, 6 splits
__global__ __launch_bounds__(256) void ksplit_reduce(const ushort* __restrict__ partb,
                                                     const float* __restrict__ x,
                                                     const float* __restrict__ bias,
                                                     const float* __restrict__ gate,
                                                     float* __restrict__ out) {
    size_t i = (size_t)blockIdx.x * 256 + threadIdx.x;
    int col = (int)((i * 8) % HID);
    float a[8] = {};
    #pragma unroll
    for (int s = 0; s < 6; ++s) {
        uint4 pv = *reinterpret_cast<const uint4*>(&partb[(size_t)s * SEQ * HID + i * 8]);
        uint w[4] = {pv.x, pv.y, pv.z, pv.w};
        #pragma unroll
        for (int c = 0; c < 4; ++c) {
            a[c * 2]     += bf2f(w[c] & 0xffffu);
            a[c * 2 + 1] += __builtin_bit_cast(float, w[c] & 0xffff0000u);
        }
    }
    f32x4 o0, o1;
    #pragma unroll
    for (int j = 0; j < 4; ++j) {
        o0[j] = x[i * 8 + j] + (a[j] + bias[col + j]) * gate[col + j];
        o1[j] = x[i * 8 + 4 + j] + (a[4 + j] + bias[col + 4 + j]) * gate[col + 4 + j];
    }
    *reinterpret_cast<f32x4*>(&out[i * 8]) = o0;
    *reinterpret_cast<f32x4*>(&out[i * 8 + 4]) = o1;
}

// ---------------- qkv post: RMSNorm(q,k) + RoPE(img rows), bf16 in -> (h,l,d) bf16 ------
__global__ __launch_bounds__(256) void qkv_post(const ushort* __restrict__ hb,
                                                const float* __restrict__ fc,
                                                const float* __restrict__ fs,
                                                const float* __restrict__ qn,
                                                const float* __restrict__ kn,
                                                __bf16* __restrict__ qb,
                                                __bf16* __restrict__ kb,
                                                __bf16* __restrict__ vb) {
    int m = blockIdx.x;
    int lane = threadIdx.x & 63, w = threadIdx.x >> 6;
    for (int rr = w; rr < 72; rr += 4) {
        int s = rr / 24, hd = rr % 24;
        const ushort* src = hb + (size_t)m * QKVW + s * HID + hd * HD;
        uint pair = *reinterpret_cast<const uint*>(&src[2 * lane]);
        float x0 = bf2f(pair & 0xffffu);
        float x1 = __builtin_bit_cast(float, pair & 0xffff0000u);
        if (s < 2) {
            float ss = x0 * x0 + x1 * x1;
            #pragma unroll
            for (int off = 1; off < 64; off <<= 1) ss += __shfl_xor(ss, off);
            float rs = rsqrtf(ss * (1.f / HD) + EPSV);
            const float* nw = (s == 0) ? qn : kn;
            x0 *= rs * nw[2 * lane];
            x1 *= rs * nw[2 * lane + 1];
            if (m < IMG) {
                float c0 = fc[m * HD + 2 * lane], c1 = fc[m * HD + 2 * lane + 1];
                float s0 = fs[m * HD + 2 * lane], s1 = fs[m * HD + 2 * lane + 1];
                float r0 = x0 * c0 - x1 * s0;
                float r1 = x1 * c1 + x0 * s1;
                x0 = r0; x1 = r1;
            }
        }
        __bf16* dst = ((s == 0) ? qb : (s == 1) ? kb : vb) + (size_t)hd * SEQ * HD + (size_t)m * HD + 2 * lane;
        uint u0 = f2bfu(x0), u1 = f2bfu(x1);
        *reinterpret_cast<uint*>(dst) = u0 | (u1 << 16);
    }
}

// ---------------- fat: flash attention (V direct from L2) + convB(w2) ----------------
__global__ __launch_bounds__(256) void attn_fat(const __bf16* __restrict__ qb,
                                                const __bf16* __restrict__ kb,
                                                const __bf16* __restrict__ vb,
                                                ushort* __restrict__ a2,
                                                const float* __restrict__ w2,
                                                ushort* __restrict__ w2b) {
    __shared__ float tle[64][65];
    int bid = blockIdx.x;
    int tid = threadIdx.x;
    if (bid >= 480) {
        int cb = bid - 480;
        conv_tile(w2, w2b, HID, A2W / 64, cb % 240, cb / 240, tid, tle);
        return;
    }
    __shared__ alignas(16) __bf16 Kl[32][136];
    __shared__ float Pl[4][32][16];

    int head = bid / 20;
    int lane = tid & 63, w = tid >> 6;
    int lr = lane & 15, lg = lane >> 4;
    int q0 = (bid % 20) * 64 + w * 16;
    const __bf16* Q = qb + (size_t)head * SEQ * HD;
    const __bf16* Kp = kb + (size_t)head * SEQ * HD;
    const __bf16* Vp = vb + (size_t)head * SEQ * HD;

    bf16x8_t qf[4];
    #pragma unroll
    for (int kc = 0; kc < 4; ++kc)
        qf[kc] = *reinterpret_cast<const bf16x8_t*>(&Q[(size_t)(q0 + lr) * HD + kc * 32 + lg * 8]);

    float m_run = -1e30f, l_run = 0.f;
    f32x4 of[8] = {};
    const float sm_scale = 0.08838834764831845f;

    for (int kv0 = 0; kv0 < SEQ; kv0 += 32) {
        // stage K only (V read direct from global/L2)
        {
            int c = tid + (tid < 256 ? 0 : 0);
            #pragma unroll
            for (int cc = 0; cc < 2; ++cc) {
                int cI = tid + cc * 256;
                int row = cI >> 4, off = (cI & 15) * 8;
                *reinterpret_cast<bf16x8_t*>(&Kl[row][off]) =
                    *reinterpret_cast<const bf16x8_t*>(&Kp[(size_t)(kv0 + row) * HD + off]);
            }
            (void)c;
        }
        __syncthreads();

        f32x4 st[2] = {};
        #pragma unroll
        for (int h = 0; h < 2; ++h)
            #pragma unroll
            for (int kc = 0; kc < 4; ++kc) {
                bf16x8_t kf = *reinterpret_cast<const bf16x8_t*>(&Kl[h * 16 + lr][kc * 32 + lg * 8]);
                st[h] = __builtin_amdgcn_mfma_f32_16x16x32_bf16(kf, qf[kc], st[h], 0, 0, 0);
            }
        float sarr[8];
        #pragma unroll
        for (int h = 0; h < 2; ++h)
            #pragma unroll
            for (int r = 0; r < 4; ++r) sarr[h * 4 + r] = st[h][r] * sm_scale;

        float mloc = sarr[0];
        #pragma unroll
        for (int i = 1; i < 8; ++i) mloc = fmaxf(mloc, sarr[i]);
        mloc = fmaxf(mloc, __shfl_xor(mloc, 16));
        mloc = fmaxf(mloc, __shfl_xor(mloc, 32));
        float m_new = fmaxf(m_run, mloc);
        float alpha = expf(m_run - m_new);
        float pv[8], psum = 0.f;
        #pragma unroll
        for (int i = 0; i < 8; ++i) { pv[i] = expf(sarr[i] - m_new); psum += pv[i]; }
        psum += __shfl_xor(psum, 16);
        psum += __shfl_xor(psum, 32);
        l_run = l_run * alpha + psum;
        m_run = m_new;

        #pragma unroll
        for (int h = 0; h < 2; ++h)
            #pragma unroll
            for (int r = 0; r < 4; ++r) Pl[w][h * 16 + lg * 4 + r][lr] = pv[h * 4 + r];
        bf16x8_t pa;
        #pragma unroll
        for (int j = 0; j < 8; ++j) pa[j] = (__bf16)Pl[w][lg * 8 + j][lr];

        float alr[4];
        #pragma unroll
        for (int r = 0; r < 4; ++r) alr[r] = __shfl(alpha, lg * 4 + r);

        #pragma unroll
        for (int db = 0; db < 8; ++db) {
            #pragma unroll
            for (int r = 0; r < 4; ++r) of[db][r] *= alr[r];
            bf16x8_t vv;
            #pragma unroll
            for (int j = 0; j < 8; ++j)
                vv[j] = Vp[(size_t)(kv0 + lg * 8 + j) * HD + db * 16 + lr];
            of[db] = __builtin_amdgcn_mfma_f32_16x16x32_bf16(pa, vv, of[db], 0, 0, 0);
        }
        __syncthreads();
    }

    float lr4[4];
    #pragma unroll
    for (int r = 0; r < 4; ++r) lr4[r] = __shfl(l_run, lg * 4 + r);
    #pragma unroll
    for (int db = 0; db < 8; ++db)
        #pragma unroll
        for (int r = 0; r < 4; ++r) {
            int row = q0 + lg * 4 + r;
            int col = head * HD + db * 16 + lr;
            a2[tpos(row, col, A2W >> 6)] = f2bfu(of[db][r] / lr4[r]);
        }
}

// ---------------- launch ----------------
extern "C" void kernel_launch(void* const* d_in, const int* in_sizes, int n_in,
                              void* d_out, int out_size, void* d_ws, size_t ws_size,
                              hipStream_t stream) {
    const float* x = (const float*)d_in[0];
    const float* vec = (const float*)d_in[1];
    const float* fc = (const float*)d_in[2];
    const float* fs = (const float*)d_in[3];
    const float* mod_w = (const float*)d_in[4];
    const float* mod_b = (const float*)d_in[5];
    const float* w1 = (const float*)d_in[6];
    const float* b1 = (const float*)d_in[7];
    const float* w2 = (const float*)d_in[8];
    const float* b2 = (const float*)d_in[9];
    const float* qn = (const float*)d_in[10];
    const float* kn = (const float*)d_in[11];
    float* out = (float*)d_out;

    char* ws = (char*)d_ws;
    size_t off = 0;
    float* sv = (float*)(ws + off); off += 3072 * 4;
    float* mod = (float*)(ws + off); off += 9216 * 4;
    float* part = (float*)(ws + off); off += 8 * 9216 * 4;
    off = (off + 255) & ~(size_t)255;
    ushort* xmt = (ushort*)(ws + off); off += (size_t)SEQ * HID * 2;      // tiled x_mod
    off = (off + 255) & ~(size_t)255;
    ushort* hqkvb = (ushort*)(ws + off); off += (size_t)SEQ * QKVW * 2;   // qkv pre-norm bf16
    __bf16* qb = (__bf16*)(ws + off); off += (size_t)NHEADS * SEQ * HD * 2;
    __bf16* kb = (__bf16*)(ws + off); off += (size_t)NHEADS * SEQ * HD * 2;
    __bf16* vb = (__bf16*)(ws + off); off += (size_t)NHEADS * SEQ * HD * 2;
    off = (off + 255) & ~(size_t)255;
    ushort* a2t = (ushort*)(ws + off); off += (size_t)SEQ * A2W * 2;      // tiled [attn|gelu]
    // bf16 k-split partials: 6 x SEQ*HID*2B = 47.19MB aliases hqkvb+qb+kb+vb exactly
    // (all four dead once gemm2 starts; a2t untouched)
    ushort* partb = hqkvb;

    off = (off + 255) & ~(size_t)255;
    ushort* w1b = (ushort*)(ws + off);   // tiled bf16 w1; w2b aliases (w1b dead after gemm1)
    ushort* w2b = w1b;

    silu_kernel<<<12, 256, 0, stream>>>(vec, sv);
    gemvconv_fat<<<288 + 48 * 336, 256, 0, stream>>>(sv, mod_w, part, w1, w1b);
    gemv_reduce<<<36, 256, 0, stream>>>(part, mod_b, mod);
    ln_mod_kernel<<<SEQ, 384, 0, stream>>>(x, mod, xmt);

    gemm8p<1, 1><<<5 * (N1 / 256), 512, 0, stream>>>(xmt, w1b, b1, hqkvb, a2t,
                                                     HID / 64, HID / 64, N1 / 256);
    qkv_post<<<SEQ, 256, 0, stream>>>(hqkvb, fc, fs, qn, kn, qb, kb, vb);
    attn_fat<<<480 + 240 * 48, 256, 0, stream>>>(qb, kb, vb, a2t, w2, w2b);
    // gemm2: SPLITS=6 -> 360 blocks (1.4 staggered rounds), NTloc = 240/6 = 40
    gemm8p<2, 6><<<6 * 5 * (HID / 256), 512, 0, stream>>>(a2t, w2b, nullptr, partb, nullptr,
                                                          A2W / 64, A2W / 64 / 6, HID / 256);
    ksplit_reduce<<<SEQ * HID / 2048, 256, 0, stream>>>(partb, x, b2, mod + 2 * HID, out);
}

// Round 15
// 598.860 us; speedup vs baseline: 1.0365x; 1.0365x over previous
//
#include <hip/hip_runtime.h>
#include <cstdint>
#include <cstddef>

typedef __bf16 bf16x8_t __attribute__((ext_vector_type(8)));
typedef float f32x4 __attribute__((ext_vector_type(4)));

#define HID 3072
#define NHEADS 24
#define HD 128
#define MLP 12288
#define SEQ 1280
#define IMG 1024
#define N1 21504   /* 3*HID + MLP */
#define QKVW 9216  /* 3*HID */
#define A2W 15360  /* HID + MLP */
#define EPSV 1e-6f

// Tiled bf16 operand layout ("fragment-block" order):
// element (row, col) of a [rows][K] operand lives at:
//   tile (row>>8, col>>6) -> 16384-elem image of 32 blocks x 512 elems:
//   block = ((col>>5)&1)*16 + ((row>>4)&15)         (k32 , row16)
//   slot  = (row&15) + ((col>>3)&3)*16              (lane = lr + lg*16)
//   elem  = block*512 + slot*8 + (col&7)
__device__ __forceinline__ size_t tpos(int row, int col, int KT) {
    return ((size_t)(row >> 8) * KT + (col >> 6)) * 16384
         + (size_t)(((((col >> 5) & 1) << 4) + ((row >> 4) & 15)) * 512
                    + (((row & 15) + (((col >> 3) & 3) << 4)) << 3) + (col & 7));
}

__device__ __forceinline__ void gload16(const void* g, void* l) {
    __builtin_amdgcn_global_load_lds(
        (const __attribute__((address_space(1))) unsigned int*)g,
        (__attribute__((address_space(3))) unsigned int*)l, 16, 0, 0);
}

__device__ __forceinline__ void bar() {
    asm volatile("" ::: "memory");
    __builtin_amdgcn_s_barrier();
    asm volatile("" ::: "memory");
}

__device__ __forceinline__ float bf2f(uint u) {
    return __builtin_bit_cast(float, u << 16);
}
__device__ __forceinline__ ushort f2bfu(float f) {
    return __builtin_bit_cast(ushort, (__bf16)f);
}

// transpose-convert tile: in [K][N] f32 -> out tiled bf16 (rows=n, cols=k), 256 thr
__device__ __forceinline__ void conv_tile(const float* __restrict__ in, ushort* __restrict__ out,
                                          int N, int KT, int kb, int nb, int tid,
                                          float (*tle)[65]) {
    int k0 = kb * 64, n0 = nb * 64;
    int rr = tid >> 2, cg = (tid & 3) * 16;
    #pragma unroll
    for (int j = 0; j < 4; ++j) {
        float4 vv = *reinterpret_cast<const float4*>(&in[(size_t)(k0 + rr) * N + n0 + cg + j * 4]);
        tle[rr][cg + j * 4 + 0] = vv.x;
        tle[rr][cg + j * 4 + 1] = vv.y;
        tle[rr][cg + j * 4 + 2] = vv.z;
        tle[rr][cg + j * 4 + 3] = vv.w;
    }
    __syncthreads();
    int nl = tid & 63;
    #pragma unroll
    for (int gg = 0; gg < 2; ++gg) {
        int g = (tid >> 6) + gg * 4;
        union { ushort u[8]; uint4 q; } pk;
        #pragma unroll
        for (int j = 0; j < 8; ++j)
            pk.u[j] = f2bfu(tle[g * 8 + j][nl]);
        *reinterpret_cast<uint4*>(&out[tpos(n0 + nl, k0 + g * 8, KT)]) = pk.q;
    }
}

// ---------------- small kernels ----------------
__global__ void silu_kernel(const float* __restrict__ v, float* __restrict__ sv) {
    int i = blockIdx.x * 256 + threadIdx.x;
    float x = v[i];
    sv[i] = x / (1.f + expf(-x));
}

// fat: blocks [0,288) = mod-GEMV partials; [288, 288+16128) = convB(w1)
__global__ __launch_bounds__(256) void gemvconv_fat(const float* __restrict__ sv,
                                                    const float* __restrict__ W,
                                                    float* __restrict__ part,
                                                    const float* __restrict__ w1,
                                                    ushort* __restrict__ w1b) {
    __shared__ float tle[64][65];
    int bid = blockIdx.x;
    int tid = threadIdx.x;
    if (bid < 288) {
        int n = (bid % 36) * 256 + tid;
        int k0 = (bid / 36) * 384;
        float s = 0.f;
        for (int k = k0; k < k0 + 384; ++k)
            s = fmaf(sv[k], W[(size_t)k * QKVW + n], s);
        part[(size_t)(bid / 36) * QKVW + n] = s;
        return;
    }
    int cb = bid - 288;
    conv_tile(w1, w1b, N1, HID / 64, cb % 48, cb / 48, tid, tle);
}

__global__ void gemv_reduce(const float* __restrict__ part, const float* __restrict__ bias,
                            float* __restrict__ mod) {
    int n = blockIdx.x * 256 + threadIdx.x;
    float s = bias[n];
    #pragma unroll
    for (int ky = 0; ky < 8; ++ky) s += part[(size_t)ky * QKVW + n];
    mod[n] = s;
}

// LayerNorm + modulate -> bf16 x_mod (tiled layout). 384 threads, 1 row/block.
__global__ __launch_bounds__(384) void ln_mod_kernel(const float* __restrict__ x,
                                                     const float* __restrict__ mod,
                                                     ushort* __restrict__ xmt) {
    int m = blockIdx.x;
    int t = threadIdx.x;
    int lane = t & 63, w = t >> 6;
    const float* xr = x + (size_t)m * HID;
    float4 v0 = *reinterpret_cast<const float4*>(&xr[t * 8]);
    float4 v1 = *reinterpret_cast<const float4*>(&xr[t * 8 + 4]);
    float s = v0.x + v0.y + v0.z + v0.w + v1.x + v1.y + v1.z + v1.w;
    float sq = v0.x * v0.x + v0.y * v0.y + v0.z * v0.z + v0.w * v0.w +
               v1.x * v1.x + v1.y * v1.y + v1.z * v1.z + v1.w * v1.w;
    #pragma unroll
    for (int off = 1; off < 64; off <<= 1) {
        s += __shfl_xor(s, off);
        sq += __shfl_xor(sq, off);
    }
    __shared__ float red[12];
    if (lane == 0) { red[w] = s; red[w + 6] = sq; }
    __syncthreads();
    s = red[0] + red[1] + red[2] + red[3] + red[4] + red[5];
    sq = red[6] + red[7] + red[8] + red[9] + red[10] + red[11];
    float mu = s * (1.f / HID);
    float var = sq * (1.f / HID) - mu * mu;
    float rs = rsqrtf(var + EPSV);
    float vals[8] = {v0.x, v0.y, v0.z, v0.w, v1.x, v1.y, v1.z, v1.w};
    union { ushort u[8]; uint4 q; } pk;
    #pragma unroll
    for (int j = 0; j < 8; ++j) {
        int n = t * 8 + j;
        float y = (vals[j] - mu) * rs * (1.f + mod[HID + n]) + mod[n];
        pk.u[j] = f2bfu(y);
    }
    *reinterpret_cast<uint4*>(&xmt[tpos(m, t * 8, HID >> 6)]) = pk.q;
}

// ---------------- 256^2 GEMM, R6 schedule + early-B prefetch (ph1) --------
// EPI==1: n<9216 -> out1 = hqkv bf16 [row][col]; else gelu -> out2 = a2t tiled
// EPI==2: out1 = bf16 partials [(sp*SEQ+row)*HID + col]
template <int EPI, int SPLITS>
__global__ __launch_bounds__(512, 2) void gemm8p(
    const ushort* __restrict__ At, const ushort* __restrict__ Bt,
    const float* __restrict__ bias, ushort* __restrict__ out1, ushort* __restrict__ out2,
    int KTtot, int NTloc, int NTN) {
    int nwg = gridDim.x;
    int q = nwg >> 3, r = nwg & 7;
    int orig = blockIdx.x;
    int xcd = orig & 7;
    int wgid = (xcd < r ? xcd * (q + 1) : r * (q + 1) + (xcd - r) * q) + (orig >> 3);
    int mt = wgid % 5;
    int p = wgid / 5;
    int nt = p % NTN;
    int sp = p / NTN;
    int kOff = sp * NTloc;
    int m0 = mt * 256, n0 = nt * 256;

    __shared__ ushort LA[2][16384];
    __shared__ ushort LB[2][16384];

    int tid = threadIdx.x;
    int lane = tid & 63, wid = tid >> 6;
    int wm = wid >> 2, wn = wid & 3;
    int lr = lane & 15, lg = lane >> 4;

    const ushort* gA = At + (size_t)mt * KTtot * 16384;
    const ushort* gB = Bt + (size_t)nt * KTtot * 16384;

    f32x4 acc[8][4] = {};
    bf16x8_t af0[4][2], af1[4][2], bf0[2][2], bf1[2][2];

    auto stage = [&](ushort (*L)[16384], int buf, const ushort* g, int ktG) {
        #pragma unroll
        for (int j = 0; j < 4; ++j) {
            int b = wid * 4 + j;
            gload16(g + (size_t)ktG * 16384 + b * 512 + lane * 8, &L[buf][b * 512]);
        }
    };
    auto rdA = [&](int buf, int h, bf16x8_t (&af)[4][2]) {
        #pragma unroll
        for (int mi = 0; mi < 4; ++mi)
            #pragma unroll
            for (int k = 0; k < 2; ++k)
                af[mi][k] = *reinterpret_cast<const bf16x8_t*>(
                    &LA[buf][(k * 16 + wm * 8 + h * 4 + mi) * 512 + lane * 8]);
    };
    auto rdB = [&](int buf, int v, bf16x8_t (&bf)[2][2]) {
        #pragma unroll
        for (int ni = 0; ni < 2; ++ni)
            #pragma unroll
            for (int k = 0; k < 2; ++k)
                bf[ni][k] = *reinterpret_cast<const bf16x8_t*>(
                    &LB[buf][(k * 16 + wn * 4 + v * 2 + ni) * 512 + lane * 8]);
    };
    auto mmq = [&](bf16x8_t (&af)[4][2], bf16x8_t (&bf)[2][2], int h, int v) {
        __builtin_amdgcn_s_setprio(1);
        #pragma unroll
        for (int mi = 0; mi < 4; ++mi)
            #pragma unroll
            for (int ni = 0; ni < 2; ++ni)
                #pragma unroll
                for (int k = 0; k < 2; ++k)
                    acc[h * 4 + mi][v * 2 + ni] = __builtin_amdgcn_mfma_f32_16x16x32_bf16(
                        af[mi][k], bf[ni][k], acc[h * 4 + mi][v * 2 + ni], 0, 0, 0);
        __builtin_amdgcn_s_setprio(0);
    };

    stage(LA, 0, gA, kOff);
    stage(LB, 0, gB, kOff);
    stage(LA, 1, gA, kOff + 1);
    stage(LB, 1, gB, kOff + 1);
    asm volatile("s_waitcnt vmcnt(8)" ::: "memory");
    bar();
    rdA(0, 0, af0);
    rdB(0, 0, bf0);

    for (int t = 0; t < NTloc; ++t) {
        int c = t & 1;
        // ph0: reads of B-half1(t) ; MFMA (0,0)
        rdB(c, 1, bf1);
        mmq(af0, bf0, 0, 0);
        bar();
        // ph1: EARLY B(t+2) prefetch into cur buf (B region dead after ph0 reads)
        if (t + 2 < NTloc) stage(LB, c, gB, kOff + t + 2);
        rdA(c, 1, af1);
        mmq(af0, bf1, 0, 1);
        bar();
        // ph2: A(t+2) prefetch ; counted vmcnt guarantees tile t+1 landed
        if (t + 2 < NTloc) stage(LA, c, gA, kOff + t + 2);
        mmq(af1, bf0, 1, 0);
        if (t + 1 < NTloc) {
            if (t + 2 < NTloc) asm volatile("s_waitcnt vmcnt(8)" ::: "memory");
            else               asm volatile("s_waitcnt vmcnt(0)" ::: "memory");
        }
        bar();
        // ph3: first fragment reads of tile t+1 ; MFMA (1,1)
        if (t + 1 < NTloc) {
            rdA(c ^ 1, 0, af0);
            rdB(c ^ 1, 0, bf0);
        }
        mmq(af1, bf1, 1, 1);
        bar();
    }

    #pragma unroll
    for (int mi8 = 0; mi8 < 8; ++mi8) {
        #pragma unroll
        for (int nj = 0; nj < 4; ++nj) {
            int col = n0 + wn * 64 + nj * 16 + lr;
            #pragma unroll
            for (int rr2 = 0; rr2 < 4; ++rr2) {
                int row = m0 + wm * 128 + mi8 * 16 + lg * 4 + rr2;
                float val = acc[mi8][nj][rr2];
                if (EPI == 1) {
                    val += bias[col];
                    if (n0 < QKVW) {
                        out1[(size_t)row * QKVW + col] = f2bfu(val);
                    } else {
                        float u = 0.7978845608028654f * (val + 0.044715f * val * val * val);
                        float g = val / (1.f + __expf(-2.f * u));
                        out2[tpos(row, HID + (col - QKVW), A2W >> 6)] = f2bfu(g);
                    }
                } else {
                    out1[(size_t)(sp * SEQ + row) * HID + col] = f2bfu(val);
                }
            }
        }
    }
}

// out = x + (sum_s bf16 part[s] + bias) * gate ; 8 elems/thread
__global__ __launch_bounds__(256) void ksplit_reduce(const ushort* __restrict__ partb,
                                                     const float* __restrict__ x,
                                                     const float* __restrict__ bias,
                                                     const float* __restrict__ gate,
                                                     float* __restrict__ out) {
    size_t i = (size_t)blockIdx.x * 256 + threadIdx.x;
    int col = (int)((i * 8) % HID);
    float a[8] = {};
    #pragma unroll
    for (int s = 0; s < 4; ++s) {
        uint4 pv = *reinterpret_cast<const uint4*>(&partb[(size_t)s * SEQ * HID + i * 8]);
        uint w[4] = {pv.x, pv.y, pv.z, pv.w};
        #pragma unroll
        for (int c = 0; c < 4; ++c) {
            a[c * 2]     += bf2f(w[c] & 0xffffu);
            a[c * 2 + 1] += __builtin_bit_cast(float, w[c] & 0xffff0000u);
        }
    }
    f32x4 o0, o1;
    #pragma unroll
    for (int j = 0; j < 4; ++j) {
        o0[j] = x[i * 8 + j] + (a[j] + bias[col + j]) * gate[col + j];
        o1[j] = x[i * 8 + 4 + j] + (a[4 + j] + bias[col + 4 + j]) * gate[col + 4 + j];
    }
    *reinterpret_cast<f32x4*>(&out[i * 8]) = o0;
    *reinterpret_cast<f32x4*>(&out[i * 8 + 4]) = o1;
}

// ---------------- qkv post: RMSNorm(q,k) + RoPE(img rows), bf16 in -> (h,l,d) bf16 ------
__global__ __launch_bounds__(256) void qkv_post(const ushort* __restrict__ hb,
                                                const float* __restrict__ fc,
                                                const float* __restrict__ fs,
                                                const float* __restrict__ qn,
                                                const float* __restrict__ kn,
                                                __bf16* __restrict__ qb,
                                                __bf16* __restrict__ kb,
                                                __bf16* __restrict__ vb) {
    int m = blockIdx.x;
    int lane = threadIdx.x & 63, w = threadIdx.x >> 6;
    for (int rr = w; rr < 72; rr += 4) {
        int s = rr / 24, hd = rr % 24;
        const ushort* src = hb + (size_t)m * QKVW + s * HID + hd * HD;
        uint pair = *reinterpret_cast<const uint*>(&src[2 * lane]);
        float x0 = bf2f(pair & 0xffffu);
        float x1 = __builtin_bit_cast(float, pair & 0xffff0000u);
        if (s < 2) {
            float ss = x0 * x0 + x1 * x1;
            #pragma unroll
            for (int off = 1; off < 64; off <<= 1) ss += __shfl_xor(ss, off);
            float rs = rsqrtf(ss * (1.f / HD) + EPSV);
            const float* nw = (s == 0) ? qn : kn;
            x0 *= rs * nw[2 * lane];
            x1 *= rs * nw[2 * lane + 1];
            if (m < IMG) {
                float c0 = fc[m * HD + 2 * lane], c1 = fc[m * HD + 2 * lane + 1];
                float s0 = fs[m * HD + 2 * lane], s1 = fs[m * HD + 2 * lane + 1];
                float r0 = x0 * c0 - x1 * s0;
                float r1 = x1 * c1 + x0 * s1;
                x0 = r0; x1 = r1;
            }
        }
        __bf16* dst = ((s == 0) ? qb : (s == 1) ? kb : vb) + (size_t)hd * SEQ * HD + (size_t)m * HD + 2 * lane;
        uint u0 = f2bfu(x0), u1 = f2bfu(x1);
        *reinterpret_cast<uint*>(dst) = u0 | (u1 << 16);
    }
}

// ---------------- fat: flash attention (tiled a2) + convB(w2) ----------------
__global__ __launch_bounds__(256) void attn_fat(const __bf16* __restrict__ qb,
                                                const __bf16* __restrict__ kb,
                                                const __bf16* __restrict__ vb,
                                                ushort* __restrict__ a2,
                                                const float* __restrict__ w2,
                                                ushort* __restrict__ w2b) {
    __shared__ float tle[64][65];
    int bid = blockIdx.x;
    int tid = threadIdx.x;
    if (bid >= 480) {
        int cb = bid - 480;
        conv_tile(w2, w2b, HID, A2W / 64, cb % 240, cb / 240, tid, tle);
        return;
    }
    __shared__ alignas(16) __bf16 Kl[32][136];
    __shared__ alignas(16) __bf16 Vl[32][136];
    __shared__ float Pl[4][32][16];

    int head = bid / 20;
    int lane = tid & 63, w = tid >> 6;
    int lr = lane & 15, lg = lane >> 4;
    int q0 = (bid % 20) * 64 + w * 16;
    const __bf16* Q = qb + (size_t)head * SEQ * HD;
    const __bf16* Kp = kb + (size_t)head * SEQ * HD;
    const __bf16* Vp = vb + (size_t)head * SEQ * HD;

    bf16x8_t qf[4];
    #pragma unroll
    for (int kc = 0; kc < 4; ++kc)
        qf[kc] = *reinterpret_cast<const bf16x8_t*>(&Q[(size_t)(q0 + lr) * HD + kc * 32 + lg * 8]);

    float m_run = -1e30f, l_run = 0.f;
    f32x4 of[8] = {};
    const float sm_scale = 0.08838834764831845f;

    for (int kv0 = 0; kv0 < SEQ; kv0 += 32) {
        #pragma unroll
        for (int cc = 0; cc < 2; ++cc) {
            int c = tid + cc * 256;
            int row = c >> 4, off = (c & 15) * 8;
            *reinterpret_cast<bf16x8_t*>(&Kl[row][off]) =
                *reinterpret_cast<const bf16x8_t*>(&Kp[(size_t)(kv0 + row) * HD + off]);
            *reinterpret_cast<bf16x8_t*>(&Vl[row][off]) =
                *reinterpret_cast<const bf16x8_t*>(&Vp[(size_t)(kv0 + row) * HD + off]);
        }
        __syncthreads();

        f32x4 st[2] = {};
        #pragma unroll
        for (int h = 0; h < 2; ++h)
            #pragma unroll
            for (int kc = 0; kc < 4; ++kc) {
                bf16x8_t kf = *reinterpret_cast<const bf16x8_t*>(&Kl[h * 16 + lr][kc * 32 + lg * 8]);
                st[h] = __builtin_amdgcn_mfma_f32_16x16x32_bf16(kf, qf[kc], st[h], 0, 0, 0);
            }
        float sarr[8];
        #pragma unroll
        for (int h = 0; h < 2; ++h)
            #pragma unroll
            for (int r = 0; r < 4; ++r) sarr[h * 4 + r] = st[h][r] * sm_scale;

        float mloc = sarr[0];
        #pragma unroll
        for (int i = 1; i < 8; ++i) mloc = fmaxf(mloc, sarr[i]);
        mloc = fmaxf(mloc, __shfl_xor(mloc, 16));
        mloc = fmaxf(mloc, __shfl_xor(mloc, 32));
        float m_new = fmaxf(m_run, mloc);
        float alpha = expf(m_run - m_new);
        float pv[8], psum = 0.f;
        #pragma unroll
        for (int i = 0; i < 8; ++i) { pv[i] = expf(sarr[i] - m_new); psum += pv[i]; }
        psum += __shfl_xor(psum, 16);
        psum += __shfl_xor(psum, 32);
        l_run = l_run * alpha + psum;
        m_run = m_new;

        #pragma unroll
        for (int h = 0; h < 2; ++h)
            #pragma unroll
            for (int r = 0; r < 4; ++r) Pl[w][h * 16 + lg * 4 + r][lr] = pv[h * 4 + r];
        bf16x8_t pa;
        #pragma unroll
        for (int j = 0; j < 8; ++j) pa[j] = (__bf16)Pl[w][lg * 8 + j][lr];

        float alr[4];
        #pragma unroll
        for (int r = 0; r < 4; ++r) alr[r] = __shfl(alpha, lg * 4 + r);

        #pragma unroll
        for (int db = 0; db < 8; ++db) {
            #pragma unroll
            for (int r = 0; r < 4; ++r) of[db][r] *= alr[r];
            bf16x8_t vv;
            #pragma unroll
            for (int j = 0; j < 8; ++j) vv[j] = Vl[lg * 8 + j][db * 16 + lr];
            of[db] = __builtin_amdgcn_mfma_f32_16x16x32_bf16(pa, vv, of[db], 0, 0, 0);
        }
        __syncthreads();
    }

    float lr4[4];
    #pragma unroll
    for (int r = 0; r < 4; ++r) lr4[r] = __shfl(l_run, lg * 4 + r);
    #pragma unroll
    for (int db = 0; db < 8; ++db)
        #pragma unroll
        for (int r = 0; r < 4; ++r) {
            int row = q0 + lg * 4 + r;
            int col = head * HD + db * 16 + lr;
            a2[tpos(row, col, A2W >> 6)] = f2bfu(of[db][r] / lr4[r]);
        }
}

// ---------------- launch ----------------
extern "C" void kernel_launch(void* const* d_in, const int* in_sizes, int n_in,
                              void* d_out, int out_size, void* d_ws, size_t ws_size,
                              hipStream_t stream) {
    const float* x = (const float*)d_in[0];
    const float* vec = (const float*)d_in[1];
    const float* fc = (const float*)d_in[2];
    const float* fs = (const float*)d_in[3];
    const float* mod_w = (const float*)d_in[4];
    const float* mod_b = (const float*)d_in[5];
    const float* w1 = (const float*)d_in[6];
    const float* b1 = (const float*)d_in[7];
    const float* w2 = (const float*)d_in[8];
    const float* b2 = (const float*)d_in[9];
    const float* qn = (const float*)d_in[10];
    const float* kn = (const float*)d_in[11];
    float* out = (float*)d_out;

    char* ws = (char*)d_ws;
    size_t off = 0;
    float* sv = (float*)(ws + off); off += 3072 * 4;
    float* mod = (float*)(ws + off); off += 9216 * 4;
    float* part = (float*)(ws + off); off += 8 * 9216 * 4;
    off = (off + 255) & ~(size_t)255;
    ushort* xmt = (ushort*)(ws + off); off += (size_t)SEQ * HID * 2;      // tiled x_mod
    off = (off + 255) & ~(size_t)255;
    ushort* hqkvb = (ushort*)(ws + off); off += (size_t)SEQ * QKVW * 2;   // qkv pre-norm bf16
    __bf16* qb = (__bf16*)(ws + off); off += (size_t)NHEADS * SEQ * HD * 2;
    __bf16* kb = (__bf16*)(ws + off); off += (size_t)NHEADS * SEQ * HD * 2;
    __bf16* vb = (__bf16*)(ws + off); off += (size_t)NHEADS * SEQ * HD * 2;
    off = (off + 255) & ~(size_t)255;
    ushort* a2t = (ushort*)(ws + off); off += (size_t)SEQ * A2W * 2;      // tiled [attn|gelu]
    // bf16 k-split partials (4*SEQ*HID*2B = 31.5MB) alias hqkvb(23.6)+qb(7.9) (dead by gemm2)
    ushort* partb = hqkvb;

    off = (off + 255) & ~(size_t)255;
    ushort* w1b = (ushort*)(ws + off);   // tiled bf16 w1; w2b aliases (w1b dead after gemm1)
    ushort* w2b = w1b;

    silu_kernel<<<12, 256, 0, stream>>>(vec, sv);
    gemvconv_fat<<<288 + 48 * 336, 256, 0, stream>>>(sv, mod_w, part, w1, w1b);
    gemv_reduce<<<36, 256, 0, stream>>>(part, mod_b, mod);
    ln_mod_kernel<<<SEQ, 384, 0, stream>>>(x, mod, xmt);

    gemm8p<1, 1><<<5 * (N1 / 256), 512, 0, stream>>>(xmt, w1b, b1, hqkvb, a2t,
                                                     HID / 64, HID / 64, N1 / 256);
    qkv_post<<<SEQ, 256, 0, stream>>>(hqkvb, fc, fs, qn, kn, qb, kb, vb);
    attn_fat<<<480 + 240 * 48, 256, 0, stream>>>(qb, kb, vb, a2t, w2, w2b);
    gemm8p<2, 4><<<4 * 5 * (HID / 256), 512, 0, stream>>>(a2t, w2b, nullptr, partb, nullptr,
                                                          A2W / 64, A2W / 64 / 4, HID / 256);
    ksplit_reduce<<<SEQ * HID / 2048, 256, 0, stream>>>(partb, x, b2, mod + 2 * HID, out);
}